// Round 1
// baseline (295.040 us; speedup 1.0000x reference)
//
#include <hip/hip_runtime.h>

#define BB 64
#define TT 512
#define HH 1024
#define CC 21
#define NROWS (BB*TT)   // 32768

// ---------------------------------------------------------------------------
// Kernel 1: emissions = hs @ W + b.  (v5 restructure)
// 512 blocks x 512 threads (8 waves); 64 rows/block, lane = row; wave w owns
// the contiguous k-slice [128w, 128w+128).
//
// vs v4: W is no longer read from LDS. Uniform ds_read_b128 broadcasts pay
// the full 64-lane VGPR writeback (~12cy each); 6144/CU/round of them made
// the K-loop LDS-writeback-bound (~61us vs 21us HBM floor). Now:
//  - W[k][*] is read at wave-uniform addresses -> compiler emits s_load
//    (SMEM co-issues with VALU, zero VALU/LDS cost). Each wave streams its
//    10.5KB W slice ONCE (single pass -> no K$ thrash, unlike R3's per-chunk
//    re-reads).
//  - hs is read per-lane straight from global: 4x float4 per 64B line with
//    the next line prefetched -> MSHR-merged, ~64KB in flight/CU (needs ~9KB
//    to saturate HBM). No LDS tile, no ds_writes, ZERO barriers in the K-loop.
//  - 1 block-round (512 blocks), LDS only 37.6KB tail scratch -> 2 blocks/CU
//    (16 waves) for latency hiding.
// ---------------------------------------------------------------------------
__global__ __launch_bounds__(512, 4) void emis_gemm(const float* __restrict__ hs,
                                                    const float* __restrict__ W,
                                                    const float* __restrict__ bias,
                                                    float* __restrict__ out) {
  __shared__ float red[7 * 1344];      // 37632 B: 7 waves' partials (wave0 sums)
  const int tid  = threadIdx.x;
  const int lane = tid & 63;
  const int w    = __builtin_amdgcn_readfirstlane(tid >> 6);
  const int row  = blockIdx.x * 64 + lane;
  const int k0   = w * 128;

  if (blockIdx.x == 0 && tid == 0) out[(size_t)NROWS * CC] = 0.f;  // loss slot

  float acc[CC];
#pragma unroll
  for (int c = 0; c < CC; ++c) acc[c] = 0.f;

  const float* p  = hs + (size_t)row * HH + k0;   // per-lane row, wave's k-slice
  const float* Wp = W  + (size_t)k0 * CC;         // wave-uniform

  float4 X[4], X2[4];
#pragma unroll
  for (int j = 0; j < 4; ++j)
    X[j] = *reinterpret_cast<const float4*>(p + 4 * j);

  // 8 line-groups of 16 k each (one 64B line per lane per group).
  for (int g = 0; g < 8; ++g) {
    if (g < 7) {                       // prefetch next 64B line (wave-uniform branch)
#pragma unroll
      for (int j = 0; j < 4; ++j)
        X2[j] = *reinterpret_cast<const float4*>(p + (g + 1) * 16 + 4 * j);
    }
    const float* wg = Wp + g * 16 * CC;
#pragma unroll
    for (int kk = 0; kk < 16; ++kk) {
      const float x = ((kk & 3) == 0) ? X[kk >> 2].x :
                      ((kk & 3) == 1) ? X[kk >> 2].y :
                      ((kk & 3) == 2) ? X[kk >> 2].z : X[kk >> 2].w;
      const float* wr = wg + kk * CC;  // wave-uniform -> s_load, SGPR fma operand
#pragma unroll
      for (int c = 0; c < CC; ++c) acc[c] = fmaf(x, wr[c], acc[c]);
    }
#pragma unroll
    for (int j = 0; j < 4; ++j) X[j] = X2[j];
  }

  // ---- cross-wave k-reduction ----
  if (w > 0) {
#pragma unroll
    for (int c = 0; c < CC; ++c)
      red[(w - 1) * 1344 + lane * CC + c] = acc[c];
  }
  __syncthreads();
  if (w == 0) {
#pragma unroll
    for (int c = 0; c < CC; ++c) {
      float v = acc[c] + bias[c];
#pragma unroll
      for (int q = 0; q < 7; ++q) v += red[q * 1344 + lane * CC + c];
      red[lane * CC + c] = v;          // in-place repack (own slots only)
    }
  }
  __syncthreads();
  for (int idx = tid; idx < 1344; idx += 512)
    out[(size_t)blockIdx.x * 1344 + idx] = red[idx];
}

// ---------------------------------------------------------------------------
// Kernel 2: CRF NLL — unchanged (isolating the GEMM change).
// ---------------------------------------------------------------------------
__global__ __launch_bounds__(128) void crf_kernel(const float* __restrict__ em,
                                                  const float* __restrict__ trans,
                                                  const float* __restrict__ startT,
                                                  const float* __restrict__ endT,
                                                  const int* __restrict__ att,
                                                  const int* __restrict__ labels,
                                                  float* __restrict__ loss) {
  const int b    = blockIdx.x;
  const int tid  = threadIdx.x;
  const int wave = tid >> 6;
  const int lane = tid & 63;
  __shared__ float sh_num;
  __shared__ int   sh_len;

  const float L2E = 1.4426950408889634f;
  const float LN2 = 0.6931471805599453f;

  if (wave == 1) {
    int cnt = 0;
    for (int t = lane; t < TT; t += 64) {
      bool m = (t == 0) || ((att[b * TT + t] != 0) && (labels[b * TT + t] != -100));
      cnt += m ? 1 : 0;
    }
#pragma unroll
    for (int off = 32; off >= 1; off >>= 1) cnt += __shfl_down(cnt, off);
    cnt = __shfl(cnt, 0);

    float s = 0.f;
    for (int t = lane + 1; t < TT; t += 64) {
      bool m = (att[b * TT + t] != 0) && (labels[b * TT + t] != -100);
      if (m) {
        int tp = labels[b * TT + t - 1], tc = labels[b * TT + t];
        s += trans[tp * CC + tc] + em[((size_t)b * TT + t) * CC + tc];
      }
    }
#pragma unroll
    for (int off = 32; off >= 1; off >>= 1) s += __shfl_down(s, off);
    if (lane == 0) {
      int tag0 = labels[b * TT];
      int lastTag = labels[b * TT + cnt - 1];
      s += startT[tag0] + em[((size_t)b * TT) * CC + tag0] + endT[lastTag];
      sh_num = s;
      sh_len = cnt;
    }
  }

  const int j = lane < CC ? lane : CC - 1;
  float E[CC];
  float beta = 0.f, endE = 0.f;
  if (wave == 0) {
#pragma unroll
    for (int i = 0; i < CC; ++i)
      E[i] = __builtin_amdgcn_exp2f(trans[i * CC + j] * L2E);
    beta = __builtin_amdgcn_exp2f((startT[j] + em[((size_t)b * TT) * CC + j]) * L2E);
    endE = __builtin_amdgcn_exp2f(endT[j] * L2E);
  }
  __syncthreads();

  if (wave == 0) {
    const int len = sh_len;
    int ksum = 0;

    float sb[CC];
#pragma unroll
    for (int i = 0; i < CC; ++i)
      sb[i] = __int_as_float(__builtin_amdgcn_readlane(__float_as_int(beta), i));

    const float* emB = em + (size_t)b * TT * CC;

    auto step = [&](float em_v) {
      float pm = __builtin_amdgcn_exp2f(em_v * L2E);
      int ef = (__float_as_int(sb[0]) >> 23) & 255;
      ksum += ef - 127;
      float pms = pm * __int_as_float((254 - ef) << 23);
      float c0 = 0.f, c1 = 0.f, c2 = 0.f;
#pragma unroll
      for (int i = 0; i < CC; i += 3) c0 = fmaf(sb[i], E[i], c0);
#pragma unroll
      for (int i = 1; i < CC; i += 3) c1 = fmaf(sb[i], E[i], c1);
#pragma unroll
      for (int i = 2; i < CC; i += 3) c2 = fmaf(sb[i], E[i], c2);
      beta = ((c0 + c1) + c2) * pms;
#pragma unroll
      for (int i = 0; i < CC; ++i)
        sb[i] = __int_as_float(__builtin_amdgcn_readlane(__float_as_int(beta), i));
    };

    float r[8];
#pragma unroll
    for (int u = 0; u < 8; ++u) {
      int tt = 1 + u; if (tt > len - 1) tt = len - 1;
      r[u] = emB[(size_t)tt * CC + j];
    }

    int t = 1;
    for (; t + 8 <= len; t += 8) {
#pragma unroll
      for (int u = 0; u < 8; ++u) {
        int tp = t + u + 8; if (tp > len - 1) tp = len - 1;
        float rn = emB[(size_t)tp * CC + j];
        step(r[u]);
        r[u] = rn;
      }
    }
    for (; t < len; ++t) {
      step(r[0]);
#pragma unroll
      for (int u = 0; u < 7; ++u) r[u] = r[u + 1];
    }

    float v = (lane < CC) ? beta * endE : 0.f;
#pragma unroll
    for (int off = 32; off >= 1; off >>= 1) v += __shfl_xor(v, off);
    if (lane == 0) {
      float logZ = (float)ksum * LN2 + LN2 * __builtin_amdgcn_logf(v);
      atomicAdd(loss, -(sh_num - logZ) * (1.0f / 64.0f));
    }
  }
}

extern "C" void kernel_launch(void* const* d_in, const int* in_sizes, int n_in,
                              void* d_out, int out_size, void* d_ws, size_t ws_size,
                              hipStream_t stream) {
  const float* hs     = (const float*)d_in[0];
  const float* W      = (const float*)d_in[1];
  const float* bias   = (const float*)d_in[2];
  const float* trans  = (const float*)d_in[3];
  const float* startT = (const float*)d_in[4];
  const float* endT   = (const float*)d_in[5];
  const int*   att    = (const int*)d_in[6];
  const int*   labels = (const int*)d_in[7];
  float* out = (float*)d_out;

  emis_gemm<<<dim3(512), dim3(512), 0, stream>>>(hs, W, bias, out);
  crf_kernel<<<dim3(64), dim3(128), 0, stream>>>(out, trans, startT, endT, att,
                                                 labels, out + (size_t)NROWS * CC);
}

// Round 2
// 287.724 us; speedup vs baseline: 1.0254x; 1.0254x over previous
//
#include <hip/hip_runtime.h>

#define BB 64
#define TT 512
#define HH 1024
#define CC 21
#define NROWS (BB*TT)   // 32768

#define AS1 __attribute__((address_space(1)))
#define AS3 __attribute__((address_space(3)))

// ---------------------------------------------------------------------------
// Kernel 1: emissions = hs @ W + b.  (v6: deep-MLP restructure)
//
// R1 post-mortem: v5 was LATENCY-bound (887 GB/s = Little's law with ~860B
// in flight/CU; VALUBusy 12.6%), plus s_load W forced lgkmcnt(0) drains.
// v6:
//  - hs staged via global_load_lds(16B) into a PER-WAVE-PRIVATE 4-slot ring,
//    3 chunks (6 KB) in flight per wave, counted vmcnt(4) (T4: never drain
//    to 0). No __syncthreads in the K-loop (ring is wave-private).
//  - W: LDS copy (86 KB), per-chunk 4 lane-divergent ds_read_b32 gathers
//    into VGPRs, broadcast per (k,c) via v_readlane (static lane index via
//    pad-32 mapping: reg = kk>>1, lane = (kk&1)*32 + c). No SMEM, no
//    broadcast ds_read writeback.
//  - 512 blocks x 512 thr (8 waves); block owns 64 rows (lane=row), wave w
//    owns k-slice [128w,128w+128) in 16 chunks of 8k. Tail = cross-wave
//    LDS reduction (ring region reused).
// LDS 148 KB -> 1 block/CU, 2 block-passes over 256 CUs.
// ---------------------------------------------------------------------------
__global__ __launch_bounds__(512, 2) void emis_gemm(const float* __restrict__ hs,
                                                    const float* __restrict__ W,
                                                    const float* __restrict__ bias,
                                                    float* __restrict__ out) {
  __shared__ float lds[21504 + 16384];   // 151552 B: W copy + 8-wave x 4-slot ring
  float* Wl   = lds;
  float* ring = lds + 21504;

  const int tid  = threadIdx.x;
  const int lane = tid & 63;
  const int w    = __builtin_amdgcn_readfirstlane(tid >> 6);
  const int row0 = blockIdx.x * 64;
  const int k0   = w * 128;

  if (blockIdx.x == 0 && tid == 0) out[(size_t)NROWS * CC] = 0.f;  // loss slot

  // ---- stage W -> LDS (row-major [1024][21], coalesced) ----
#pragma unroll
  for (int i = 0; i < 42; ++i) Wl[tid + i * 512] = W[tid + i * 512];

  // W-gather per-lane float-indices: padded idx = j*64+lane -> (kk,c)
  int gidx[4];
#pragma unroll
  for (int j = 0; j < 4; ++j) {
    int idx = j * 64 + lane;
    int kk  = idx >> 5;
    int c   = idx & 31; if (c > 20) c = 20;   // clamp pad lanes (never readlane'd)
    gidx[j] = (k0 + kk) * CC + c;
  }

  // per-lane global src for staging: lane l -> row (l>>1), k-half (l&1)
  const float* gsrcA = hs + (size_t)(row0 + (lane >> 1)) * HH + k0 + (lane & 1) * 4;
  const float* gsrcB = gsrcA + (size_t)32 * HH;
  float* ringw = ring + w * 2048;           // 4 slots x 512 floats (64 rows x 8k)

  __syncthreads();                          // W visible to all waves

  float acc[CC];
#pragma unroll
  for (int c = 0; c < CC; ++c) acc[c] = 0.f;

  // ---- prologue: stage chunks 0,1,2 (3 in flight = 6 loads) ----
#pragma unroll
  for (int c = 0; c < 3; ++c) {
    float* dst = ringw + c * 512;
    __builtin_amdgcn_global_load_lds((const AS1 unsigned int*)(gsrcA + c * 8),
                                     (AS3 unsigned int*)dst, 16, 0, 0);
    __builtin_amdgcn_global_load_lds((const AS1 unsigned int*)(gsrcB + c * 8),
                                     (AS3 unsigned int*)(dst + 256), 16, 0, 0);
  }

  auto chunk_body = [&](int c) {
    // stage chunk c+3 into slot (c+3)&3 (never the slot being read)
    if (c < 13) {
      float* dst = ringw + ((c + 3) & 3) * 512;
      __builtin_amdgcn_global_load_lds((const AS1 unsigned int*)(gsrcA + (c + 3) * 8),
                                       (AS3 unsigned int*)dst, 16, 0, 0);
      __builtin_amdgcn_global_load_lds((const AS1 unsigned int*)(gsrcB + (c + 3) * 8),
                                       (AS3 unsigned int*)(dst + 256), 16, 0, 0);
    }
    // x: this lane's row, 8 k (two b128)
    const float* tl = ringw + (c & 3) * 512 + lane * 8;
    float4 xa = *reinterpret_cast<const float4*>(tl);
    float4 xb = *reinterpret_cast<const float4*>(tl + 4);
    // W chunk: 4 lane-divergent gathers (8k x 21c distributed, pad-32 map)
    float vws[4];
#pragma unroll
    for (int j = 0; j < 4; ++j) { vws[j] = Wl[gidx[j]]; gidx[j] += 8 * CC; }

    float xs[8] = {xa.x, xa.y, xa.z, xa.w, xb.x, xb.y, xb.z, xb.w};
#pragma unroll
    for (int kk = 0; kk < 8; ++kk) {
      const float x  = xs[kk];
      const int   lb = (kk & 1) * 32;
#pragma unroll
      for (int cc = 0; cc < CC; ++cc) {
        const float wv = __int_as_float(
            __builtin_amdgcn_readlane(__float_as_int(vws[kk >> 1]), lb + cc));
        acc[cc] = fmaf(x, wv, acc[cc]);
      }
    }
  };

  // ---- main loop: counted vmcnt, zero barriers ----
  for (int c = 0; c < 14; ++c) {
    __builtin_amdgcn_sched_barrier(0);
    asm volatile("s_waitcnt vmcnt(4)" ::: "memory");   // chunk c staged (2 newer stages stay in flight)
    __builtin_amdgcn_sched_barrier(0);
    chunk_body(c);
  }
  __builtin_amdgcn_sched_barrier(0);
  asm volatile("s_waitcnt vmcnt(2)" ::: "memory");
  __builtin_amdgcn_sched_barrier(0);
  chunk_body(14);
  __builtin_amdgcn_sched_barrier(0);
  asm volatile("s_waitcnt vmcnt(0)" ::: "memory");
  __builtin_amdgcn_sched_barrier(0);
  chunk_body(15);

  // ---- cross-wave k-reduction (reuse ring region) ----
  __syncthreads();
  float* red = ring;
  if (w > 0) {
#pragma unroll
    for (int c = 0; c < CC; ++c)
      red[(w - 1) * 1344 + lane * CC + c] = acc[c];
  }
  __syncthreads();
  if (w == 0) {
#pragma unroll
    for (int c = 0; c < CC; ++c) {
      float v = acc[c] + bias[c];
#pragma unroll
      for (int q = 0; q < 7; ++q) v += red[q * 1344 + lane * CC + c];
      red[7 * 1344 + lane * CC + c] = v;
    }
  }
  __syncthreads();
  for (int idx = tid; idx < 1344; idx += 512)
    out[(size_t)blockIdx.x * 1344 + idx] = red[7 * 1344 + idx];
}

// ---------------------------------------------------------------------------
// Kernel 2: CRF NLL — unchanged (isolating the GEMM change).
// ---------------------------------------------------------------------------
__global__ __launch_bounds__(128) void crf_kernel(const float* __restrict__ em,
                                                  const float* __restrict__ trans,
                                                  const float* __restrict__ startT,
                                                  const float* __restrict__ endT,
                                                  const int* __restrict__ att,
                                                  const int* __restrict__ labels,
                                                  float* __restrict__ loss) {
  const int b    = blockIdx.x;
  const int tid  = threadIdx.x;
  const int wave = tid >> 6;
  const int lane = tid & 63;
  __shared__ float sh_num;
  __shared__ int   sh_len;

  const float L2E = 1.4426950408889634f;
  const float LN2 = 0.6931471805599453f;

  if (wave == 1) {
    int cnt = 0;
    for (int t = lane; t < TT; t += 64) {
      bool m = (t == 0) || ((att[b * TT + t] != 0) && (labels[b * TT + t] != -100));
      cnt += m ? 1 : 0;
    }
#pragma unroll
    for (int off = 32; off >= 1; off >>= 1) cnt += __shfl_down(cnt, off);
    cnt = __shfl(cnt, 0);

    float s = 0.f;
    for (int t = lane + 1; t < TT; t += 64) {
      bool m = (att[b * TT + t] != 0) && (labels[b * TT + t] != -100);
      if (m) {
        int tp = labels[b * TT + t - 1], tc = labels[b * TT + t];
        s += trans[tp * CC + tc] + em[((size_t)b * TT + t) * CC + tc];
      }
    }
#pragma unroll
    for (int off = 32; off >= 1; off >>= 1) s += __shfl_down(s, off);
    if (lane == 0) {
      int tag0 = labels[b * TT];
      int lastTag = labels[b * TT + cnt - 1];
      s += startT[tag0] + em[((size_t)b * TT) * CC + tag0] + endT[lastTag];
      sh_num = s;
      sh_len = cnt;
    }
  }

  const int j = lane < CC ? lane : CC - 1;
  float E[CC];
  float beta = 0.f, endE = 0.f;
  if (wave == 0) {
#pragma unroll
    for (int i = 0; i < CC; ++i)
      E[i] = __builtin_amdgcn_exp2f(trans[i * CC + j] * L2E);
    beta = __builtin_amdgcn_exp2f((startT[j] + em[((size_t)b * TT) * CC + j]) * L2E);
    endE = __builtin_amdgcn_exp2f(endT[j] * L2E);
  }
  __syncthreads();

  if (wave == 0) {
    const int len = sh_len;
    int ksum = 0;

    float sb[CC];
#pragma unroll
    for (int i = 0; i < CC; ++i)
      sb[i] = __int_as_float(__builtin_amdgcn_readlane(__float_as_int(beta), i));

    const float* emB = em + (size_t)b * TT * CC;

    auto step = [&](float em_v) {
      float pm = __builtin_amdgcn_exp2f(em_v * L2E);
      int ef = (__float_as_int(sb[0]) >> 23) & 255;
      ksum += ef - 127;
      float pms = pm * __int_as_float((254 - ef) << 23);
      float c0 = 0.f, c1 = 0.f, c2 = 0.f;
#pragma unroll
      for (int i = 0; i < CC; i += 3) c0 = fmaf(sb[i], E[i], c0);
#pragma unroll
      for (int i = 1; i < CC; i += 3) c1 = fmaf(sb[i], E[i], c1);
#pragma unroll
      for (int i = 2; i < CC; i += 3) c2 = fmaf(sb[i], E[i], c2);
      beta = ((c0 + c1) + c2) * pms;
#pragma unroll
      for (int i = 0; i < CC; ++i)
        sb[i] = __int_as_float(__builtin_amdgcn_readlane(__float_as_int(beta), i));
    };

    float r[8];
#pragma unroll
    for (int u = 0; u < 8; ++u) {
      int tt = 1 + u; if (tt > len - 1) tt = len - 1;
      r[u] = emB[(size_t)tt * CC + j];
    }

    int t = 1;
    for (; t + 8 <= len; t += 8) {
#pragma unroll
      for (int u = 0; u < 8; ++u) {
        int tp = t + u + 8; if (tp > len - 1) tp = len - 1;
        float rn = emB[(size_t)tp * CC + j];
        step(r[u]);
        r[u] = rn;
      }
    }
    for (; t < len; ++t) {
      step(r[0]);
#pragma unroll
      for (int u = 0; u < 7; ++u) r[u] = r[u + 1];
    }

    float v = (lane < CC) ? beta * endE : 0.f;
#pragma unroll
    for (int off = 32; off >= 1; off >>= 1) v += __shfl_xor(v, off);
    if (lane == 0) {
      float logZ = (float)ksum * LN2 + LN2 * __builtin_amdgcn_logf(v);
      atomicAdd(loss, -(sh_num - logZ) * (1.0f / 64.0f));
    }
  }
}

extern "C" void kernel_launch(void* const* d_in, const int* in_sizes, int n_in,
                              void* d_out, int out_size, void* d_ws, size_t ws_size,
                              hipStream_t stream) {
  const float* hs     = (const float*)d_in[0];
  const float* W      = (const float*)d_in[1];
  const float* bias   = (const float*)d_in[2];
  const float* trans  = (const float*)d_in[3];
  const float* startT = (const float*)d_in[4];
  const float* endT   = (const float*)d_in[5];
  const int*   att    = (const int*)d_in[6];
  const int*   labels = (const int*)d_in[7];
  float* out = (float*)d_out;

  emis_gemm<<<dim3(512), dim3(512), 0, stream>>>(hs, W, bias, out);
  crf_kernel<<<dim3(64), dim3(128), 0, stream>>>(out, trans, startT, endT, att,
                                                 labels, out + (size_t)NROWS * CC);
}

// Round 3
// 282.114 us; speedup vs baseline: 1.0458x; 1.0199x over previous
//
#include <hip/hip_runtime.h>

#define BB 64
#define TT 512
#define HH 1024
#define CC 21
#define NROWS (BB*TT)   // 32768

#define AS1 __attribute__((address_space(1)))
#define AS3 __attribute__((address_space(3)))

// ---------------------------------------------------------------------------
// Kernel 1: emissions = hs @ W + b.  (v7: coalesced staging)
//
// R2 post-mortem: v4/v5/v6 all ~78us. Not BW (0.9 of 6.8 TB/s), not VALU
// (35%), not in-flight bytes (40KB/CU >> Little's-law need). Common factor:
// every VMEM instruction scattered over 32-64 distinct 4KB-strided rows ->
// per-instruction address-divergence throttles the TA/L1 path and delays
// vmcnt retirement. v7 makes every staging instruction CONTIGUOUS:
//  - chunk = 64 rows x 128 k (32KB), staged by 32 global_load_lds of 1KB
//    each (lanes 0-31 = row 2i, lanes 32-63 = row 2i+1 -> 2 contiguous 512B
//    segments per instruction, vs 32-64 before).
//  - LDS tile [64 rows][128 floats], dest linear (required by
//    global_load_lds); bank-conflict-free compute reads via SOURCE-side XOR
//    pre-swizzle: LDS[row][s] holds global slot s^(row&7)  (16B units), so
//    ds_read_b128 at slot (k4 ^ (row&7)) is octet-conflict-free.
//  - compute: lane=row; wave w owns k-slice [w*16,w*16+16) of each chunk;
//    W broadcast per (k,c) via v_readlane from 8 VGPRs gathered per chunk
//    (8 divergent ds_read_b32, pad-32 map). Cross-wave k-reduce at end.
//  - 2-phase schedule (T3 minimum): stage(c+1) -> compute(c) -> barrier.
//    Load latency (~900cy) hides under compute (~1400cy).
// LDS: W 86KB + 2x32KB tile = 150.5KB -> 1 block/CU; 512 blocks, 2 passes.
// ---------------------------------------------------------------------------
__global__ __launch_bounds__(512, 2) void emis_gemm(const float* __restrict__ hs,
                                                    const float* __restrict__ W,
                                                    const float* __restrict__ bias,
                                                    float* __restrict__ out) {
  __shared__ float lds[21504 + 2 * 8192];   // 151552 B
  float* Wl   = lds;
  float* tile = lds + 21504;                // 2 buffers of 8192 floats

  const int tid  = threadIdx.x;
  const int lane = tid & 63;
  const int w    = __builtin_amdgcn_readfirstlane(tid >> 6);
  const int row0 = blockIdx.x * 64;

  if (blockIdx.x == 0 && tid == 0) out[(size_t)NROWS * CC] = 0.f;  // loss slot

  // ---- stage W -> LDS (21504 floats, coalesced, linear) ----
#pragma unroll
  for (int i = 0; i < 42; ++i) Wl[tid + i * 512] = W[tid + i * 512];

  // ---- W-gather indices (pad-32 map): 16k x 21c -> 512 slots -> 8 regs ----
  int gidx[8];
#pragma unroll
  for (int j = 0; j < 8; ++j) {
    int slot = j * 64 + lane;
    int kk   = slot >> 5;
    int c    = slot & 31; if (c > 20) c = 20;    // pad lanes (never readlane'd)
    gidx[j] = (w * 16 + kk) * CC + c;            // chunk 0; += 128*CC per chunk
  }

  // ---- staging source ptrs: this wave's 4 instrs cover rows 2i,2i+1 ----
  // lane: half=lane>>5 picks the row, s=lane&31 is the 16B slot; source slot
  // pre-swizzled s^(row&7) so linear LDS dest yields swizzled layout.
  const float* gs[4];
#pragma unroll
  for (int ii = 0; ii < 4; ++ii) {
    int i   = w * 4 + ii;
    int row = 2 * i + (lane >> 5);
    int ss  = (lane & 31) ^ (row & 7);
    gs[ii] = hs + (size_t)(row0 + row) * HH + ss * 4;
  }

  float acc[CC];
#pragma unroll
  for (int c = 0; c < CC; ++c) acc[c] = 0.f;

  auto stage = [&](int c, int b) {   // chunk c -> buffer b (4 instrs, 1KB each)
    float* dst = tile + b * 8192 + (w * 4) * 256;
#pragma unroll
    for (int ii = 0; ii < 4; ++ii)
      __builtin_amdgcn_global_load_lds((const AS1 unsigned int*)(gs[ii] + c * 128),
                                       (AS3 unsigned int*)(dst + ii * 256), 16, 0, 0);
  };

  auto compute = [&](int b) {        // consume buffer b (this wave's k-slice)
    float vws[8];
#pragma unroll
    for (int j = 0; j < 8; ++j) { vws[j] = Wl[gidx[j]]; gidx[j] += 128 * CC; }

    const float* tb = tile + b * 8192 + lane * 128;
    float4 X[4];
#pragma unroll
    for (int q = 0; q < 4; ++q) {
      int slot = (w * 4 + q) ^ (lane & 7);       // un-swizzle
      X[q] = *reinterpret_cast<const float4*>(tb + slot * 4);
    }
#pragma unroll
    for (int q = 0; q < 4; ++q) {
      float xs[4] = {X[q].x, X[q].y, X[q].z, X[q].w};
#pragma unroll
      for (int t = 0; t < 4; ++t) {
        const int   kk  = q * 4 + t;             // 0..15
        const float x   = xs[t];
        const int   reg = kk >> 1;
        const int   lb  = (kk & 1) * 32;
#pragma unroll
        for (int cc = 0; cc < CC; ++cc) {
          const float wv = __int_as_float(
              __builtin_amdgcn_readlane(__float_as_int(vws[reg]), lb + cc));
          acc[cc] = fmaf(x, wv, acc[cc]);
        }
      }
    }
  };

  // ---- 2-phase pipeline: stage(c+1) || compute(c), one barrier per chunk ----
  stage(0, 0);
  __syncthreads();                    // chunk0 staged + W visible
  for (int c = 0; c < 8; ++c) {
    if (c < 7) stage(c + 1, (c + 1) & 1);
    __builtin_amdgcn_sched_barrier(0);   // pin stage issue before compute
    compute(c & 1);
    __syncthreads();                  // c+1 loads done; buf (c&1) free to reuse
  }

  // ---- cross-wave k-reduction (reuse tile region) ----
  float* red = tile;
  if (w > 0) {
#pragma unroll
    for (int c = 0; c < CC; ++c)
      red[(w - 1) * 1344 + lane * CC + c] = acc[c];
  }
  __syncthreads();
  if (w == 0) {
#pragma unroll
    for (int c = 0; c < CC; ++c) {
      float v = acc[c] + bias[c];
#pragma unroll
      for (int q = 0; q < 7; ++q) v += red[q * 1344 + lane * CC + c];
      red[7 * 1344 + lane * CC + c] = v;
    }
  }
  __syncthreads();
  for (int idx = tid; idx < 1344; idx += 512)
    out[(size_t)blockIdx.x * 1344 + idx] = red[7 * 1344 + idx];
}

// ---------------------------------------------------------------------------
// Kernel 2: CRF NLL — unchanged (isolating the GEMM change).
// ---------------------------------------------------------------------------
__global__ __launch_bounds__(128) void crf_kernel(const float* __restrict__ em,
                                                  const float* __restrict__ trans,
                                                  const float* __restrict__ startT,
                                                  const float* __restrict__ endT,
                                                  const int* __restrict__ att,
                                                  const int* __restrict__ labels,
                                                  float* __restrict__ loss) {
  const int b    = blockIdx.x;
  const int tid  = threadIdx.x;
  const int wave = tid >> 6;
  const int lane = tid & 63;
  __shared__ float sh_num;
  __shared__ int   sh_len;

  const float L2E = 1.4426950408889634f;
  const float LN2 = 0.6931471805599453f;

  if (wave == 1) {
    int cnt = 0;
    for (int t = lane; t < TT; t += 64) {
      bool m = (t == 0) || ((att[b * TT + t] != 0) && (labels[b * TT + t] != -100));
      cnt += m ? 1 : 0;
    }
#pragma unroll
    for (int off = 32; off >= 1; off >>= 1) cnt += __shfl_down(cnt, off);
    cnt = __shfl(cnt, 0);

    float s = 0.f;
    for (int t = lane + 1; t < TT; t += 64) {
      bool m = (att[b * TT + t] != 0) && (labels[b * TT + t] != -100);
      if (m) {
        int tp = labels[b * TT + t - 1], tc = labels[b * TT + t];
        s += trans[tp * CC + tc] + em[((size_t)b * TT + t) * CC + tc];
      }
    }
#pragma unroll
    for (int off = 32; off >= 1; off >>= 1) s += __shfl_down(s, off);
    if (lane == 0) {
      int tag0 = labels[b * TT];
      int lastTag = labels[b * TT + cnt - 1];
      s += startT[tag0] + em[((size_t)b * TT) * CC + tag0] + endT[lastTag];
      sh_num = s;
      sh_len = cnt;
    }
  }

  const int j = lane < CC ? lane : CC - 1;
  float E[CC];
  float beta = 0.f, endE = 0.f;
  if (wave == 0) {
#pragma unroll
    for (int i = 0; i < CC; ++i)
      E[i] = __builtin_amdgcn_exp2f(trans[i * CC + j] * L2E);
    beta = __builtin_amdgcn_exp2f((startT[j] + em[((size_t)b * TT) * CC + j]) * L2E);
    endE = __builtin_amdgcn_exp2f(endT[j] * L2E);
  }
  __syncthreads();

  if (wave == 0) {
    const int len = sh_len;
    int ksum = 0;

    float sb[CC];
#pragma unroll
    for (int i = 0; i < CC; ++i)
      sb[i] = __int_as_float(__builtin_amdgcn_readlane(__float_as_int(beta), i));

    const float* emB = em + (size_t)b * TT * CC;

    auto step = [&](float em_v) {
      float pm = __builtin_amdgcn_exp2f(em_v * L2E);
      int ef = (__float_as_int(sb[0]) >> 23) & 255;
      ksum += ef - 127;
      float pms = pm * __int_as_float((254 - ef) << 23);
      float c0 = 0.f, c1 = 0.f, c2 = 0.f;
#pragma unroll
      for (int i = 0; i < CC; i += 3) c0 = fmaf(sb[i], E[i], c0);
#pragma unroll
      for (int i = 1; i < CC; i += 3) c1 = fmaf(sb[i], E[i], c1);
#pragma unroll
      for (int i = 2; i < CC; i += 3) c2 = fmaf(sb[i], E[i], c2);
      beta = ((c0 + c1) + c2) * pms;
#pragma unroll
      for (int i = 0; i < CC; ++i)
        sb[i] = __int_as_float(__builtin_amdgcn_readlane(__float_as_int(beta), i));
    };

    float r[8];
#pragma unroll
    for (int u = 0; u < 8; ++u) {
      int tt = 1 + u; if (tt > len - 1) tt = len - 1;
      r[u] = emB[(size_t)tt * CC + j];
    }

    int t = 1;
    for (; t + 8 <= len; t += 8) {
#pragma unroll
      for (int u = 0; u < 8; ++u) {
        int tp = t + u + 8; if (tp > len - 1) tp = len - 1;
        float rn = emB[(size_t)tp * CC + j];
        step(r[u]);
        r[u] = rn;
      }
    }
    for (; t < len; ++t) {
      step(r[0]);
#pragma unroll
      for (int u = 0; u < 7; ++u) r[u] = r[u + 1];
    }

    float v = (lane < CC) ? beta * endE : 0.f;
#pragma unroll
    for (int off = 32; off >= 1; off >>= 1) v += __shfl_xor(v, off);
    if (lane == 0) {
      float logZ = (float)ksum * LN2 + LN2 * __builtin_amdgcn_logf(v);
      atomicAdd(loss, -(sh_num - logZ) * (1.0f / 64.0f));
    }
  }
}

extern "C" void kernel_launch(void* const* d_in, const int* in_sizes, int n_in,
                              void* d_out, int out_size, void* d_ws, size_t ws_size,
                              hipStream_t stream) {
  const float* hs     = (const float*)d_in[0];
  const float* W      = (const float*)d_in[1];
  const float* bias   = (const float*)d_in[2];
  const float* trans  = (const float*)d_in[3];
  const float* startT = (const float*)d_in[4];
  const float* endT   = (const float*)d_in[5];
  const int*   att    = (const int*)d_in[6];
  const int*   labels = (const int*)d_in[7];
  float* out = (float*)d_out;

  emis_gemm<<<dim3(512), dim3(512), 0, stream>>>(hs, W, bias, out);
  crf_kernel<<<dim3(64), dim3(128), 0, stream>>>(out, trans, startT, endT, att,
                                                 labels, out + (size_t)NROWS * CC);
}